// Round 4
// baseline (47.914 us; speedup 1.0000x reference)
//
#include <hip/hip_runtime.h>

typedef float f2 __attribute__((ext_vector_type(2)));

#define DD 128
#define HH 256
#define WW 256
#define OD 127
#define NCHUNK 16
#define DCHUNK 8
#define SLICE_F (HH*WW)
#define NBIN 64

struct Raw { float4 p0, p1, p2, t0, t1, t2; };
// Per-slice state for a wave's 2 row-pairs. f2 = (pair0, pair1).
struct Sl  { f2 uu2[4]; f2 vv2[4]; f2 ps[4]; };

__device__ __forceinline__ void make_sl(const Raw R, Sl& S)
{
    // u = e^x ; sigma = u/(1+u) ; 1-sigma = 1/(1+u)
    float u0x=__expf(R.p0.x), u0y=__expf(R.p0.y), u0z=__expf(R.p0.z), u0w=__expf(R.p0.w);
    float u1x=__expf(R.p1.x), u1y=__expf(R.p1.y), u1z=__expf(R.p1.z), u1w=__expf(R.p1.w);
    float u2x=__expf(R.p2.x), u2y=__expf(R.p2.y), u2z=__expf(R.p2.z), u2w=__expf(R.p2.w);

    f2 uA0 = {u0x,u1x}, uB0 = {u1x,u2x};
    f2 uA1 = {u0y,u1y}, uB1 = {u1y,u2y};
    f2 uA2 = {u0z,u1z}, uB2 = {u1z,u2z};
    f2 uA3 = {u0w,u1w}, uB3 = {u1w,u2w};

    f2 W0 = uA0*uB0, W1 = uA1*uB1, W2 = uA2*uB2, W3 = uA3*uB3;
    f2 Q0 = (uA0+1.f)*(uB0+1.f);
    f2 Q1 = (uA1+1.f)*(uB1+1.f);
    f2 Q2 = (uA2+1.f)*(uB2+1.f);
    f2 Q3 = (uA3+1.f)*(uB3+1.f);
    f2 W4, Q4;
    W4.x = __shfl_down(W0.x, 1); W4.y = __shfl_down(W0.y, 1);  // lane+1 col0 = our col4
    Q4.x = __shfl_down(Q0.x, 1); Q4.y = __shfl_down(Q0.y, 1);

    S.uu2[0]=W0*W1; S.uu2[1]=W1*W2; S.uu2[2]=W2*W3; S.uu2[3]=W3*W4;
    S.vv2[0]=Q0*Q1; S.vv2[1]=Q1*Q2; S.vv2[2]=Q2*Q3; S.vv2[3]=Q3*Q4;

    // target column sums (exact small ints in f32); only pop is ever needed
    f2 cs0 = {R.t0.x+R.t1.x, R.t1.x+R.t2.x};
    f2 cs1 = {R.t0.y+R.t1.y, R.t1.y+R.t2.y};
    f2 cs2 = {R.t0.z+R.t1.z, R.t1.z+R.t2.z};
    f2 cs3 = {R.t0.w+R.t1.w, R.t1.w+R.t2.w};
    f2 cs4; cs4.x = __shfl_down(cs0.x, 1); cs4.y = __shfl_down(cs0.y, 1);
    S.ps[0]=cs0+cs1; S.ps[1]=cs1+cs2; S.ps[2]=cs2+cs3; S.ps[3]=cs3+cs4;
}

__device__ __forceinline__ void do_cubes(const Sl& P, const Sl& C,
        const f2 vAll, const f2 v3,
        f2& aFG, f2& aF255, f2& aBG, f2& aBG0, f2& aSFA,
        f2& c255, f2& c0, f2& cMN)
{
    #pragma unroll
    for (int j = 0; j < 4; ++j) {
        f2 E = P.uu2[j] * C.uu2[j];
        f2 Q = P.vv2[j] * C.vv2[j];
        f2 vj = (j == 3) ? v3 : vAll;
        f2 r; r.x = __builtin_amdgcn_rcpf(Q.x); r.y = __builtin_amdgcn_rcpf(Q.y);
        r *= vj;                         // masks lane63 j3 + invalid row1; bg = r
        f2 fg = E * r;
        f2 pop = P.ps[j] + C.ps[j];      // exact 0..8
        f2 i255, i0, mn;
        i255.x = fmaxf(pop.x - 7.f, 0.f); i255.y = fmaxf(pop.y - 7.f, 0.f); // ==1 iff pop==8
        i0.x   = fmaxf(1.f - pop.x, 0.f); i0.y   = fmaxf(1.f - pop.y, 0.f); // ==1 iff pop==0
        mn.x   = 4.f - fabsf(pop.x - 4.f); mn.y = 4.f - fabsf(pop.y - 4.f); // min(pop,8-pop)=2*area
        mn *= vj;
        aFG  += fg;
        aBG  += r;
        aF255 = fg * i255 + aF255;
        aBG0  = r  * i0   + aBG0;
        c255  = i255 * vj + c255;
        c0    = i0   * vj + c0;
        aSFA  = (fg + r) * mn + aSFA;
        cMN  += mn;
    }
}

#define LOADR(R, pP, pT) do { \
    R.p0 = *(const float4*)(pP); R.p1 = *(const float4*)((pP) + WW); R.p2 = *(const float4*)((pP) + r2off); \
    R.t0 = *(const float4*)(pT); R.t1 = *(const float4*)((pT) + WW); R.t2 = *(const float4*)((pT) + r2off); \
} while (0)

#define ADV(pP, pT, dn) do { \
    if ((dn) + 2 < DD) { pP += 2*SLICE_F; pT += 2*SLICE_F; dn += 2; } \
} while (0)

// ws layout: [NBIN][2 batches][8 sums]
// 0 sum(fg) 1 sum(fg*gtfg) 2 cnt(gtfg) 3 sum(bg) 4 sum(bg*gtbg) 5 cnt(gtbg)
// 6 sum((fg+bg)*2a) 7 sum(2a)
__global__ __launch_bounds__(256)
void loss_main(const float* __restrict__ preds,
               const float* __restrict__ targets,
               float* __restrict__ ws)
{
    const int lane = threadIdx.x & 63;
    const int wv   = threadIdx.x >> 6;
    const int h0   = ((blockIdx.x << 2) + wv) << 1;   // 0..254, cube rows h0, h0+1
    const int b    = blockIdx.z;
    const int d0   = blockIdx.y * DCHUNK;
    const int dend = min(d0 + DCHUNK, OD);

    const size_t colBase = (size_t)b * DD * SLICE_F + (size_t)h0 * WW + (size_t)(lane << 2);
    const int   r2off = (h0 + 2 < HH) ? 2*WW : WW;        // clamp input row 256 (masked)
    const float rv1   = (h0 + 1 < HH - 1) ? 1.f : 0.f;    // cube row h0+1 validity
    const float v63   = (lane == 63) ? 0.f : 1.f;         // cube col 255 (j==3) validity
    const f2 vAll = {1.f, rv1};
    const f2 v3   = {v63, v63 * rv1};

    const float* pP0 = preds   + colBase + (size_t)d0 * SLICE_F;
    const float* pT0 = targets + colBase + (size_t)d0 * SLICE_F;
    const float* pP1 = pP0 + SLICE_F;
    const float* pT1 = pT0 + SLICE_F;
    int dn0 = d0, dn1 = d0 + 1;

    f2 aFG={0,0}, aF255={0,0}, aBG={0,0}, aBG0={0,0}, aSFA={0,0};
    f2 c255={0,0}, c0={0,0}, cMN={0,0};

    Raw R0, R1; Sl A, B;
    LOADR(R0, pP0, pT0); ADV(pP0, pT0, dn0);
    LOADR(R1, pP1, pT1); ADV(pP1, pT1, dn1);
    __builtin_amdgcn_sched_barrier(0);
    make_sl(R0, A);
    LOADR(R0, pP0, pT0); ADV(pP0, pT0, dn0);
    __builtin_amdgcn_sched_barrier(0);

    int d = d0;
    for (; d + 2 <= dend; d += 2) {
        make_sl(R1, B);                                   // slice d+1
        LOADR(R1, pP1, pT1); ADV(pP1, pT1, dn1);          // prefetch slice d+3
        __builtin_amdgcn_sched_barrier(0);
        do_cubes(A, B, vAll, v3, aFG, aF255, aBG, aBG0, aSFA, c255, c0, cMN);
        make_sl(R0, A);                                   // slice d+2
        LOADR(R0, pP0, pT0); ADV(pP0, pT0, dn0);          // prefetch slice d+4
        __builtin_amdgcn_sched_barrier(0);
        do_cubes(B, A, vAll, v3, aFG, aF255, aBG, aBG0, aSFA, c255, c0, cMN);
    }
    if (d < dend) {
        make_sl(R1, B);
        do_cubes(A, B, vAll, v3, aFG, aF255, aBG, aBG0, aSFA, c255, c0, cMN);
    }

    float acc[8] = {aFG.x+aFG.y, aF255.x+aF255.y, c255.x+c255.y,
                    aBG.x+aBG.y, aBG0.x+aBG0.y,   c0.x+c0.y,
                    aSFA.x+aSFA.y, cMN.x+cMN.y};
    #pragma unroll
    for (int i = 0; i < 8; ++i) {
        float v = acc[i];
        #pragma unroll
        for (int off = 32; off > 0; off >>= 1) v += __shfl_xor(v, off);
        acc[i] = v;
    }
    float mine = acc[0];
    mine = (lane == 1) ? acc[1] : mine;
    mine = (lane == 2) ? acc[2] : mine;
    mine = (lane == 3) ? acc[3] : mine;
    mine = (lane == 4) ? acc[4] : mine;
    mine = (lane == 5) ? acc[5] : mine;
    mine = (lane == 6) ? acc[6] : mine;
    mine = (lane == 7) ? acc[7] : mine;
    if (lane < 8) {
        int bin = (blockIdx.x + blockIdx.y) & (NBIN - 1);
        atomicAdd(&ws[(bin * 2 + b) * 8 + lane], mine);
    }
}

__global__ void loss_final(const float* __restrict__ ws, float* __restrict__ out)
{
    __shared__ float s[16];
    const int t = threadIdx.x;
    if (t < 16) {
        float v = 0.f;
        #pragma unroll 4
        for (int x = 0; x < NBIN; ++x) v += ws[x * 16 + t];
        s[t] = v;
    }
    __syncthreads();
    if (t == 0) {
        const float eps = 1e-5f;
        float dice = 0.f;
        #pragma unroll
        for (int b = 0; b < 2; ++b) {
            const float* q = s + b * 8;
            float fg_dice = (2.f*q[1] + eps) / (q[0] + q[2] + eps);
            float bg_dice = (2.f*q[4] + eps) / (q[3] + q[5] + eps);
            float q6 = 0.5f * q[6];            // restore area = 0.5*min(pop,8-pop)
            float q7 = 0.5f * q[7];
            float ss = q7 - q6;                // sum(surf*area)
            float sf_dice = (2.f*ss + eps) / (ss + q7 + eps);
            dice += fg_dice + bg_dice + sf_dice;
        }
        out[0] = 1.f - dice * (1.f/6.f);
    }
}

extern "C" void kernel_launch(void* const* d_in, const int* in_sizes, int n_in,
                              void* d_out, int out_size, void* d_ws, size_t ws_size,
                              hipStream_t stream)
{
    const float* preds   = (const float*)d_in[0];
    const float* targets = (const float*)d_in[1];
    // d_in[2] power / d_in[3] kernel / d_in[4] area are analytic -- baked in
    float* ws = (float*)d_ws;

    hipMemsetAsync(ws, 0, NBIN * 16 * sizeof(float), stream);

    dim3 grid(32, NCHUNK, 2);   // 1024 blocks = 4/CU
    loss_main<<<grid, 256, 0, stream>>>(preds, targets, ws);
    loss_final<<<1, 64, 0, stream>>>(ws, (float*)d_out);
}

// Round 5
// 44.321 us; speedup vs baseline: 1.0811x; 1.0811x over previous
//
#include <hip/hip_runtime.h>

typedef float f2 __attribute__((ext_vector_type(2)));

#define DD 128
#define HH 256
#define WW 256
#define OD 127
#define SLICE_F (HH*WW)
#define NBIN 64
#define DCH 8          // d-chunks
#define CHUNK 16       // layers per chunk (last: 15)
#define STAGE_B 20480  // bytes per staged slice: 10 rows x 1KB x 2 tensors
#define NBUF 3

#define VMCNT5() asm volatile("s_waitcnt vmcnt(5)" ::: "memory")
#define VMCNT0() asm volatile("s_waitcnt vmcnt(0)" ::: "memory")

struct Sl { f2 uu2[4]; f2 vv2[4]; f2 ps[4]; };

// stage one (b,slice): 10 pred rows + 10 targ rows -> LDS buf. 5 loads/wave.
__device__ __forceinline__ void stage_slice(const float* __restrict__ pB,
                                            const float* __restrict__ tB,
                                            int slice, char* lb,
                                            int h0, int wv, int lane)
{
    #pragma unroll
    for (int i = 0; i < 5; ++i) {
        const int L = i * 4 + wv;            // 0..19, unique per (i,wv)
        const int T = (L >= 10) ? 1 : 0;     // 0=pred 1=targ
        const int r = L - T * 10;            // row slot 0..9 (9 = dummy dup)
        const int grow = min(h0 + r, HH - 1);
        const float* g = (T ? tB : pB)
                       + ((size_t)slice << 16) + (grow << 8) + (lane << 2);
        void* l = lb + T * 10240 + r * 1024 + lane * 16;
        __builtin_amdgcn_global_load_lds(
            (const __attribute__((address_space(1))) void*)g,
            (__attribute__((address_space(3))) void*)l, 16, 0, 0);
    }
}

__device__ __forceinline__ void make_sl_lds(const char* buf, int wv, int lane, Sl& S)
{
    const float* sp = (const float*)buf;
    const float* st = (const float*)(buf + 10240);
    const int ro = ((wv << 1) << 8) + (lane << 2);   // row 2*wv, col lane*4
    const float4 p0 = *(const float4*)(sp + ro);
    const float4 p1 = *(const float4*)(sp + ro + 256);
    const float4 p2 = *(const float4*)(sp + ro + 512);
    const float4 t0 = *(const float4*)(st + ro);
    const float4 t1 = *(const float4*)(st + ro + 256);
    const float4 t2 = *(const float4*)(st + ro + 512);

    // u = e^x ; sigma = u/(1+u) ; 1-sigma = 1/(1+u)
    float u0x=__expf(p0.x), u0y=__expf(p0.y), u0z=__expf(p0.z), u0w=__expf(p0.w);
    float u1x=__expf(p1.x), u1y=__expf(p1.y), u1z=__expf(p1.z), u1w=__expf(p1.w);
    float u2x=__expf(p2.x), u2y=__expf(p2.y), u2z=__expf(p2.z), u2w=__expf(p2.w);

    f2 uA0 = {u0x,u1x}, uB0 = {u1x,u2x};
    f2 uA1 = {u0y,u1y}, uB1 = {u1y,u2y};
    f2 uA2 = {u0z,u1z}, uB2 = {u1z,u2z};
    f2 uA3 = {u0w,u1w}, uB3 = {u1w,u2w};

    f2 W0 = uA0*uB0, W1 = uA1*uB1, W2 = uA2*uB2, W3 = uA3*uB3;
    f2 Q0 = (uA0+1.f)*(uB0+1.f);
    f2 Q1 = (uA1+1.f)*(uB1+1.f);
    f2 Q2 = (uA2+1.f)*(uB2+1.f);
    f2 Q3 = (uA3+1.f)*(uB3+1.f);
    f2 W4, Q4;
    W4.x = __shfl_down(W0.x, 1); W4.y = __shfl_down(W0.y, 1);
    Q4.x = __shfl_down(Q0.x, 1); Q4.y = __shfl_down(Q0.y, 1);

    S.uu2[0]=W0*W1; S.uu2[1]=W1*W2; S.uu2[2]=W2*W3; S.uu2[3]=W3*W4;
    S.vv2[0]=Q0*Q1; S.vv2[1]=Q1*Q2; S.vv2[2]=Q2*Q3; S.vv2[3]=Q3*Q4;

    f2 cs0 = {t0.x+t1.x, t1.x+t2.x};
    f2 cs1 = {t0.y+t1.y, t1.y+t2.y};
    f2 cs2 = {t0.z+t1.z, t1.z+t2.z};
    f2 cs3 = {t0.w+t1.w, t1.w+t2.w};
    f2 cs4; cs4.x = __shfl_down(cs0.x, 1); cs4.y = __shfl_down(cs0.y, 1);
    S.ps[0]=cs0+cs1; S.ps[1]=cs1+cs2; S.ps[2]=cs2+cs3; S.ps[3]=cs3+cs4;
}

__device__ __forceinline__ void do_cubes(const Sl& P, const Sl& C,
        const f2 vAll, const f2 v3,
        f2& aFG, f2& aF255, f2& aBG, f2& aBG0, f2& aSFA,
        f2& c255, f2& c0, f2& cMN)
{
    #pragma unroll
    for (int j = 0; j < 4; ++j) {
        f2 E = P.uu2[j] * C.uu2[j];
        f2 Q = P.vv2[j] * C.vv2[j];
        f2 vj = (j == 3) ? v3 : vAll;
        f2 r; r.x = __builtin_amdgcn_rcpf(Q.x); r.y = __builtin_amdgcn_rcpf(Q.y);
        r *= vj;
        f2 fg = E * r;
        f2 pop = P.ps[j] + C.ps[j];      // exact 0..8
        f2 i255, i0, mn;
        i255.x = fmaxf(pop.x - 7.f, 0.f); i255.y = fmaxf(pop.y - 7.f, 0.f);
        i0.x   = fmaxf(1.f - pop.x, 0.f); i0.y   = fmaxf(1.f - pop.y, 0.f);
        mn.x   = 4.f - fabsf(pop.x - 4.f); mn.y = 4.f - fabsf(pop.y - 4.f);
        mn *= vj;
        aFG  += fg;
        aBG  += r;
        aF255 = fg * i255 + aF255;
        aBG0  = r  * i0   + aBG0;
        c255  = i255 * vj + c255;
        c0    = i0   * vj + c0;
        aSFA  = (fg + r) * mn + aSFA;
        cMN  += mn;
    }
}

// ws layout: [NBIN][2 batches][8 sums]
__global__ __launch_bounds__(256)
void loss_main(const float* __restrict__ preds,
               const float* __restrict__ targets,
               float* __restrict__ ws)
{
    __shared__ __align__(16) char smem[NBUF * STAGE_B];   // 60 KB

    const int lane = threadIdx.x & 63;
    const int wv   = threadIdx.x >> 6;
    const int h0   = blockIdx.x << 3;        // 8 cube rows per block
    const int b    = blockIdx.z;
    const int d0   = blockIdx.y * CHUNK;
    const int NT   = min(CHUNK, OD - d0);    // 16 or 15 layers

    const float* pB = preds   + (size_t)b * DD * SLICE_F;
    const float* tB = targets + (size_t)b * DD * SLICE_F;

    const int   myrow = h0 + (wv << 1);
    const float rv1 = (myrow + 1 < HH - 1) ? 1.f : 0.f;   // cube row myrow+1
    const float v63 = (lane == 63) ? 0.f : 1.f;
    const f2 vAll = {1.f, rv1};
    const f2 v3   = {v63, v63 * rv1};

    f2 aFG={0,0}, aF255={0,0}, aBG={0,0}, aBG0={0,0}, aSFA={0,0};
    f2 c255={0,0}, c0={0,0}, cMN={0,0};

    // prologue: stage slices d0, d0+1
    stage_slice(pB, tB, d0,     smem,           h0, wv, lane);
    stage_slice(pB, tB, d0 + 1, smem + STAGE_B, h0, wv, lane);
    VMCNT5();                                  // slice d0 landed
    __builtin_amdgcn_s_barrier();
    __builtin_amdgcn_sched_barrier(0);

    Sl A, B;
    make_sl_lds(smem, wv, lane, A);            // slice d0 -> A

    int t = 0, bn = 1;                         // bn = buf of slice t+1
    for (;;) {
        {   // even layer t: cubes from A (slice t) x B (slice t+1)
            int bs = bn + 1; if (bs >= NBUF) bs = 0;
            if (t + 2 <= NT) {
                stage_slice(pB, tB, d0 + t + 2, smem + bs * STAGE_B, h0, wv, lane);
                VMCNT5();
            } else VMCNT0();
            __builtin_amdgcn_s_barrier();
            __builtin_amdgcn_sched_barrier(0);
            make_sl_lds(smem + bn * STAGE_B, wv, lane, B);
            do_cubes(A, B, vAll, v3, aFG, aF255, aBG, aBG0, aSFA, c255, c0, cMN);
            if (++t >= NT) break;
            bn = bs;
        }
        {   // odd layer t: cubes from B x A
            int bs = bn + 1; if (bs >= NBUF) bs = 0;
            if (t + 2 <= NT) {
                stage_slice(pB, tB, d0 + t + 2, smem + bs * STAGE_B, h0, wv, lane);
                VMCNT5();
            } else VMCNT0();
            __builtin_amdgcn_s_barrier();
            __builtin_amdgcn_sched_barrier(0);
            make_sl_lds(smem + bn * STAGE_B, wv, lane, A);
            do_cubes(B, A, vAll, v3, aFG, aF255, aBG, aBG0, aSFA, c255, c0, cMN);
            if (++t >= NT) break;
            bn = bs;
        }
    }

    float acc[8] = {aFG.x+aFG.y, aF255.x+aF255.y, c255.x+c255.y,
                    aBG.x+aBG.y, aBG0.x+aBG0.y,   c0.x+c0.y,
                    aSFA.x+aSFA.y, cMN.x+cMN.y};
    #pragma unroll
    for (int i = 0; i < 8; ++i) {
        float v = acc[i];
        #pragma unroll
        for (int off = 32; off > 0; off >>= 1) v += __shfl_xor(v, off);
        acc[i] = v;
    }
    float mine = acc[0];
    mine = (lane == 1) ? acc[1] : mine;
    mine = (lane == 2) ? acc[2] : mine;
    mine = (lane == 3) ? acc[3] : mine;
    mine = (lane == 4) ? acc[4] : mine;
    mine = (lane == 5) ? acc[5] : mine;
    mine = (lane == 6) ? acc[6] : mine;
    mine = (lane == 7) ? acc[7] : mine;
    if (lane < 8) {
        int bin = (blockIdx.x + (blockIdx.y << 5)) & (NBIN - 1);
        atomicAdd(&ws[(bin * 2 + b) * 8 + lane], mine);
    }
}

__global__ void loss_final(const float* __restrict__ ws, float* __restrict__ out)
{
    __shared__ float s[16];
    const int t = threadIdx.x;
    if (t < 16) {
        float v = 0.f;
        #pragma unroll 4
        for (int x = 0; x < NBIN; ++x) v += ws[x * 16 + t];
        s[t] = v;
    }
    __syncthreads();
    if (t == 0) {
        const float eps = 1e-5f;
        float dice = 0.f;
        #pragma unroll
        for (int b = 0; b < 2; ++b) {
            const float* q = s + b * 8;
            float fg_dice = (2.f*q[1] + eps) / (q[0] + q[2] + eps);
            float bg_dice = (2.f*q[4] + eps) / (q[3] + q[5] + eps);
            float q6 = 0.5f * q[6];          // area = 0.5*min(pop,8-pop)
            float q7 = 0.5f * q[7];
            float ss = q7 - q6;              // sum(surf*area)
            float sf_dice = (2.f*ss + eps) / (ss + q7 + eps);
            dice += fg_dice + bg_dice + sf_dice;
        }
        out[0] = 1.f - dice * (1.f/6.f);
    }
}

extern "C" void kernel_launch(void* const* d_in, const int* in_sizes, int n_in,
                              void* d_out, int out_size, void* d_ws, size_t ws_size,
                              hipStream_t stream)
{
    const float* preds   = (const float*)d_in[0];
    const float* targets = (const float*)d_in[1];
    // d_in[2] power / d_in[3] kernel / d_in[4] area are analytic -- baked in
    float* ws = (float*)d_ws;

    hipMemsetAsync(ws, 0, NBIN * 16 * sizeof(float), stream);

    dim3 grid(32, DCH, 2);   // 512 blocks = exactly 2 resident/CU (LDS-capped)
    loss_main<<<grid, 256, 0, stream>>>(preds, targets, ws);
    loss_final<<<1, 64, 0, stream>>>(ws, (float*)d_out);
}

// Round 6
// 40.772 us; speedup vs baseline: 1.1752x; 1.0870x over previous
//
#include <hip/hip_runtime.h>

typedef float f2 __attribute__((ext_vector_type(2)));

#define DD 128
#define HH 256
#define WW 256
#define OD 127
#define SLICE_F (HH*WW)
#define NBIN 64
#define CHUNK 8        // layers per d-chunk (16 chunks)
#define ROWS_B 9216    // 9 rows x 1KB per tensor
#define STAGE_B 18432  // pred 9 rows + targ 9 rows
#define NBUF 2

#define VMCNT0() asm volatile("s_waitcnt vmcnt(0)" ::: "memory")

struct Sl { f2 uu2[4]; f2 vv2[4]; f2 ps[4]; };

// stage one slice: 9 pred rows + 9 targ rows -> LDS. waves 0,1: 5 loads; 2,3: 4.
__device__ __forceinline__ void stage_slice(const float* __restrict__ pB,
                                            const float* __restrict__ tB,
                                            int slice, char* lb,
                                            int h0, int wv, int lane)
{
    #pragma unroll
    for (int i = 0; i < 5; ++i) {
        if (i == 4 && wv >= 2) break;        // wave-uniform
        const int L = i * 4 + wv;            // 0..17
        const int T = (L >= 9) ? 1 : 0;      // 0=pred 1=targ
        const int r = L - T * 9;             // row slot 0..8
        const int grow = min(h0 + r, HH - 1);
        const float* g = (T ? tB : pB)
                       + ((size_t)slice << 16) + (grow << 8) + (lane << 2);
        void* l = lb + T * ROWS_B + r * 1024 + lane * 16;
        __builtin_amdgcn_global_load_lds(
            (const __attribute__((address_space(1))) void*)g,
            (__attribute__((address_space(3))) void*)l, 16, 0, 0);
    }
}

__device__ __forceinline__ void make_sl_lds(const char* buf, int wv, int lane, Sl& S)
{
    const float* sp = (const float*)buf;
    const float* st = (const float*)(buf + ROWS_B);
    const int ro = ((wv << 1) << 8) + (lane << 2);   // row 2*wv, col lane*4
    const float4 p0 = *(const float4*)(sp + ro);
    const float4 p1 = *(const float4*)(sp + ro + 256);
    const float4 p2 = *(const float4*)(sp + ro + 512);
    const float4 t0 = *(const float4*)(st + ro);
    const float4 t1 = *(const float4*)(st + ro + 256);
    const float4 t2 = *(const float4*)(st + ro + 512);

    float u0x=__expf(p0.x), u0y=__expf(p0.y), u0z=__expf(p0.z), u0w=__expf(p0.w);
    float u1x=__expf(p1.x), u1y=__expf(p1.y), u1z=__expf(p1.z), u1w=__expf(p1.w);
    float u2x=__expf(p2.x), u2y=__expf(p2.y), u2z=__expf(p2.z), u2w=__expf(p2.w);

    f2 uA0 = {u0x,u1x}, uB0 = {u1x,u2x};
    f2 uA1 = {u0y,u1y}, uB1 = {u1y,u2y};
    f2 uA2 = {u0z,u1z}, uB2 = {u1z,u2z};
    f2 uA3 = {u0w,u1w}, uB3 = {u1w,u2w};

    f2 W0 = uA0*uB0, W1 = uA1*uB1, W2 = uA2*uB2, W3 = uA3*uB3;
    f2 Q0 = (uA0+1.f)*(uB0+1.f);
    f2 Q1 = (uA1+1.f)*(uB1+1.f);
    f2 Q2 = (uA2+1.f)*(uB2+1.f);
    f2 Q3 = (uA3+1.f)*(uB3+1.f);
    f2 W4, Q4;
    W4.x = __shfl_down(W0.x, 1); W4.y = __shfl_down(W0.y, 1);
    Q4.x = __shfl_down(Q0.x, 1); Q4.y = __shfl_down(Q0.y, 1);

    S.uu2[0]=W0*W1; S.uu2[1]=W1*W2; S.uu2[2]=W2*W3; S.uu2[3]=W3*W4;
    S.vv2[0]=Q0*Q1; S.vv2[1]=Q1*Q2; S.vv2[2]=Q2*Q3; S.vv2[3]=Q3*Q4;

    f2 cs0 = {t0.x+t1.x, t1.x+t2.x};
    f2 cs1 = {t0.y+t1.y, t1.y+t2.y};
    f2 cs2 = {t0.z+t1.z, t1.z+t2.z};
    f2 cs3 = {t0.w+t1.w, t1.w+t2.w};
    f2 cs4; cs4.x = __shfl_down(cs0.x, 1); cs4.y = __shfl_down(cs0.y, 1);
    S.ps[0]=cs0+cs1; S.ps[1]=cs1+cs2; S.ps[2]=cs2+cs3; S.ps[3]=cs3+cs4;
}

__device__ __forceinline__ void do_cubes(const Sl& P, const Sl& C,
        const f2 vAll, const f2 v3,
        f2& aFG, f2& aF255, f2& aBG, f2& aBG0, f2& aSFA,
        f2& c255, f2& c0, f2& cMN)
{
    #pragma unroll
    for (int j = 0; j < 4; ++j) {
        f2 E = P.uu2[j] * C.uu2[j];
        f2 Q = P.vv2[j] * C.vv2[j];
        f2 vj = (j == 3) ? v3 : vAll;
        f2 r; r.x = __builtin_amdgcn_rcpf(Q.x); r.y = __builtin_amdgcn_rcpf(Q.y);
        r *= vj;
        f2 fg = E * r;
        f2 pop = P.ps[j] + C.ps[j];      // exact 0..8
        f2 i255, i0, mn;
        i255.x = fmaxf(pop.x - 7.f, 0.f); i255.y = fmaxf(pop.y - 7.f, 0.f);
        i0.x   = fmaxf(1.f - pop.x, 0.f); i0.y   = fmaxf(1.f - pop.y, 0.f);
        mn.x   = 4.f - fabsf(pop.x - 4.f); mn.y = 4.f - fabsf(pop.y - 4.f);
        mn *= vj;
        aFG  += fg;
        aBG  += r;
        aF255 = fg * i255 + aF255;
        aBG0  = r  * i0   + aBG0;
        c255  = i255 * vj + c255;
        c0    = i0   * vj + c0;
        aSFA  = (fg + r) * mn + aSFA;
        cMN  += mn;
    }
}

#define LAYER(SRC, DST, STAGE_OFF, READ_OFF)                                   \
    do {                                                                       \
        VMCNT0();                                                              \
        __builtin_amdgcn_s_barrier();                                          \
        __builtin_amdgcn_sched_barrier(0);                                     \
        if (t + 2 <= NT)                                                       \
            stage_slice(pB, tB, d0 + t + 2, smem + (STAGE_OFF), h0, wv, lane); \
        make_sl_lds(smem + (READ_OFF), wv, lane, DST);                         \
        do_cubes(SRC, DST, vAll, v3, aFG, aF255, aBG, aBG0, aSFA, c255, c0, cMN); \
    } while (0)

// ws layout: [NBIN][2 batches][8 sums]
__global__ __launch_bounds__(256, 4)
void loss_main(const float* __restrict__ preds,
               const float* __restrict__ targets,
               float* __restrict__ ws)
{
    __shared__ __align__(16) char smem[NBUF * STAGE_B];   // 36 KB -> 4 blocks/CU

    const int lane = threadIdx.x & 63;
    const int wv   = threadIdx.x >> 6;

    // bijective XCD-chunked swizzle: 1024 blocks, 8 XCDs, 128 contiguous per XCD
    const int nid = ((blockIdx.x & 7) << 7) + (blockIdx.x >> 3);
    const int x = nid & 31;            // h-slab
    const int y = (nid >> 5) & 15;     // d-chunk
    const int b = nid >> 9;            // batch

    const int h0 = x << 3;             // 8 cube rows per block
    const int d0 = y << 3;
    const int NT = min(CHUNK, OD - d0);

    const float* pB = preds   + (size_t)b * DD * SLICE_F;
    const float* tB = targets + (size_t)b * DD * SLICE_F;

    const int   myrow = h0 + (wv << 1);
    const float rv1 = (myrow + 1 < HH - 1) ? 1.f : 0.f;
    const float v63 = (lane == 63) ? 0.f : 1.f;
    const f2 vAll = {1.f, rv1};
    const f2 v3   = {v63, v63 * rv1};

    f2 aFG={0,0}, aF255={0,0}, aBG={0,0}, aBG0={0,0}, aSFA={0,0};
    f2 c255={0,0}, c0={0,0}, cMN={0,0};

    // prologue: stage slices 0,1 of the chunk
    stage_slice(pB, tB, d0,     smem,           h0, wv, lane);
    stage_slice(pB, tB, d0 + 1, smem + STAGE_B, h0, wv, lane);
    VMCNT0();
    __builtin_amdgcn_s_barrier();
    __builtin_amdgcn_sched_barrier(0);

    Sl A, B;
    make_sl_lds(smem, wv, lane, A);    // slice 0 -> A

    int t = 0;
    for (;;) {
        // even layer t: stage t+2 -> buf0, read slice t+1 from buf1
        LAYER(A, B, 0, STAGE_B);
        if (++t >= NT) break;
        // odd layer t: stage t+2 -> buf1, read slice t+1 from buf0
        LAYER(B, A, STAGE_B, 0);
        if (++t >= NT) break;
    }

    float acc[8] = {aFG.x+aFG.y, aF255.x+aF255.y, c255.x+c255.y,
                    aBG.x+aBG.y, aBG0.x+aBG0.y,   c0.x+c0.y,
                    aSFA.x+aSFA.y, cMN.x+cMN.y};
    #pragma unroll
    for (int i = 0; i < 8; ++i) {
        float v = acc[i];
        #pragma unroll
        for (int off = 32; off > 0; off >>= 1) v += __shfl_xor(v, off);
        acc[i] = v;
    }
    float mine = acc[0];
    mine = (lane == 1) ? acc[1] : mine;
    mine = (lane == 2) ? acc[2] : mine;
    mine = (lane == 3) ? acc[3] : mine;
    mine = (lane == 4) ? acc[4] : mine;
    mine = (lane == 5) ? acc[5] : mine;
    mine = (lane == 6) ? acc[6] : mine;
    mine = (lane == 7) ? acc[7] : mine;
    if (lane < 8) {
        int bin = nid & (NBIN - 1);
        atomicAdd(&ws[(bin * 2 + b) * 8 + lane], mine);
    }
}

__global__ void loss_final(const float* __restrict__ ws, float* __restrict__ out)
{
    __shared__ float s[16];
    const int t = threadIdx.x;
    if (t < 16) {
        float v = 0.f;
        #pragma unroll 4
        for (int x = 0; x < NBIN; ++x) v += ws[x * 16 + t];
        s[t] = v;
    }
    __syncthreads();
    if (t == 0) {
        const float eps = 1e-5f;
        float dice = 0.f;
        #pragma unroll
        for (int b = 0; b < 2; ++b) {
            const float* q = s + b * 8;
            float fg_dice = (2.f*q[1] + eps) / (q[0] + q[2] + eps);
            float bg_dice = (2.f*q[4] + eps) / (q[3] + q[5] + eps);
            float q6 = 0.5f * q[6];          // area = 0.5*min(pop,8-pop)
            float q7 = 0.5f * q[7];
            float ss = q7 - q6;              // sum(surf*area)
            float sf_dice = (2.f*ss + eps) / (ss + q7 + eps);
            dice += fg_dice + bg_dice + sf_dice;
        }
        out[0] = 1.f - dice * (1.f/6.f);
    }
}

extern "C" void kernel_launch(void* const* d_in, const int* in_sizes, int n_in,
                              void* d_out, int out_size, void* d_ws, size_t ws_size,
                              hipStream_t stream)
{
    const float* preds   = (const float*)d_in[0];
    const float* targets = (const float*)d_in[1];
    // d_in[2] power / d_in[3] kernel / d_in[4] area are analytic -- baked in
    float* ws = (float*)d_ws;

    hipMemsetAsync(ws, 0, NBIN * 16 * sizeof(float), stream);

    loss_main<<<1024, 256, 0, stream>>>(preds, targets, ws);   // 4 blocks/CU exact
    loss_final<<<1, 64, 0, stream>>>(ws, (float*)d_out);
}